// Round 12
// baseline (199.517 us; speedup 1.0000x reference)
//
#include <hip/hip_runtime.h>
#include <math.h>

// B,C,T = 32,1024,1024; beta=0.95; thr=1.0; sigma=10.5
#define B_     32
#define C_     1024
#define T_     1024
#define RT     92                 // tap radius (|d|>92 cannot flip any f32 spike; r2-r11)
#define CT     64                 // channels per block
#define TT     64                 // time chunk
#define KC     4                  // channels per thread
#define NG     16                 // groups (16 x 32 threads = 512)
#define WOFF   (RT + KC - 1)      // 95: tap idx = d + 95, il = L + 3 - k
#define NWT    192                // tap floats (48 quads), idx 0..190 used
#define NCOLS  (CT + 2*RT)        // 248 staged channel columns
#define NRP    (TT/2)             // 32 row-pairs
#define XSTR2  500                // dwords per row-pair (250 f2, 16B-aligned rows)
#define ISTR   66                 // strip row stride (dwords, even for b64)
#define NF4    (NCOLS * (TT/4))   // 3968 staged float4s per chunk

typedef float f32x2 __attribute__((ext_vector_type(2)));
typedef float f32x4 __attribute__((ext_vector_type(4)));

// numpy-faithful f32 tap (identical op sequence; exp via correctly-rounded f64).
__device__ __forceinline__ float tap_value(float s, int d) {
    float u    = __fdiv_rn((float)d, s);
    float t1   = __fmul_rn(-0.5f, u);
    float t2   = __fmul_rn(t1, u);
    float e    = (float)exp((double)t2);
    float den  = __fmul_rn(s, sqrtf(6.2831854820251465f));
    float coef = __fdiv_rn(1.0f, den);
    return __fmul_rn(coef, e);
}

#define EL(v, i) ((i) == 0 ? (v).x : (i) == 1 ? (v).y : (i) == 2 ? (v).z : (v).w)
#define SEL4(T0, T1, T2, T3, il)                                                \
    ((il) < 4 ? EL(T0, (il)) : (il) < 8 ? EL(T1, (il) - 4)                      \
              : (il) < 12 ? EL(T2, (il) - 8) : EL(T3, (il) - 12))

#if __has_builtin(__builtin_elementwise_fma)
#define PKFMA(W2, X2, A2) __builtin_elementwise_fma((W2), (X2), (A2))
#else
#define PKFMA(W2, X2, A2) (f32x2){fmaf((W2).x,(X2).x,(A2).x), fmaf((W2).y,(X2).y,(A2).y)}
#endif

// One column L (both t's packed): 4 pk-fma, taps compile-time from T0..T3.
#define COLSTEP(XP, ILB, T0, T1, T2, T3)                                        \
    do {                                                                        \
        _Pragma("unroll")                                                       \
        for (int k = 0; k < KC; ++k) {                                          \
            const int il = (ILB) + 3 - k;                                       \
            float wv = SEL4(T0, T1, T2, T3, il);                                \
            f32x2 w2 = {wv, wv};                                                \
            acc[k] = PKFMA(w2, XP, acc[k]);                                     \
        }                                                                       \
    } while (0)

// One b128 x-read = cols (2r,2r+1) x 2 t. Ascending col order.
#define STEP2(XV, LL, T0, T1, T2, T3)                                           \
    do {                                                                        \
        f32x2 xlo_ = (XV).xy;                                                   \
        f32x2 xhi_ = (XV).zw;                                                   \
        COLSTEP(xlo_, (LL),     T0, T1, T2, T3);                                \
        COLSTEP(xhi_, (LL) + 1, T0, T1, T2, T3);                                \
    } while (0)

// Full pass: 12 cols (6 b128), taps w[12P..12P+15] in 4 quads.
#define PASS(P)                                                                 \
    do {                                                                        \
        f32x4 T0 = wq4[3*(P)+0], T1 = wq4[3*(P)+1];                             \
        f32x4 T2 = wq4[3*(P)+2], T3 = wq4[3*(P)+3];                             \
        f32x4 x0 = xr4[6*(P)+0], x1 = xr4[6*(P)+1], x2 = xr4[6*(P)+2];          \
        f32x4 x3 = xr4[6*(P)+3], x4 = xr4[6*(P)+4], x5 = xr4[6*(P)+5];          \
        STEP2(x0, 0, T0, T1, T2, T3); STEP2(x1, 2,  T0, T1, T2, T3);            \
        STEP2(x2, 4, T0, T1, T2, T3); STEP2(x3, 6,  T0, T1, T2, T3);            \
        STEP2(x4, 8, T0, T1, T2, T3); STEP2(x5, 10, T0, T1, T2, T3);            \
    } while (0)

// Last pass: 8 cols (4 b128), taps w[180..191] in 3 quads (il <= 10).
#define PASSL()                                                                 \
    do {                                                                        \
        f32x4 T0 = wq4[45], T1 = wq4[46], T2 = wq4[47];                         \
        f32x4 x0 = xr4[90], x1 = xr4[91], x2 = xr4[92], x3 = xr4[93];           \
        STEP2(x0, 0, T0, T1, T2, T2); STEP2(x1, 2, T0, T1, T2, T2);             \
        STEP2(x2, 4, T0, T1, T2, T2); STEP2(x3, 6, T0, T1, T2, T2);             \
    } while (0)

// t-interleaved tile xsT2[t/2][col][2]: one b128 = 2 cols x 2 t, pk-ready.
// Thread (tp,g): channels c0+4g+k at t in {2tp, 2tp+1}. Wave-local strips.
__global__ __launch_bounds__(512, 4) void snn_v12(
    const float* __restrict__ x, const float* __restrict__ sigma,
    float* __restrict__ out)
{
    __shared__ __align__(16) float xsT2[NRP * XSTR2];   // 64000 B
    __shared__ __align__(16) float IsS[NG * KC * ISTR]; // 16896 B
    __shared__ __align__(16) float wtap[NWT];           //   768 B (total 81664)

    const int tp   = threadIdx.x;      // t-pair lane 0..31
    const int g    = threadIdx.y;      // channel group 0..15
    const int flat = g * 32 + tp;
    const int b    = blockIdx.y;
    const int c0   = blockIdx.x * CT;

    // ---- per-block tap table (bit-identical values to all passing rounds) ----
    if (flat < NWT) {
        int d = flat - WOFF;
        wtap[flat] = (d >= -RT && d <= RT) ? tap_value(sigma[0], d) : 0.0f;
    }

    const float* xb = x   + (size_t)b * ((size_t)C_ * T_);
    float*       ob = out + (size_t)b * ((size_t)C_ * T_);

    f32x4 stg[8];                      // statically indexed only (rule #20)

#define STAGE_LOAD(T0_)                                                         \
    _Pragma("unroll")                                                           \
    for (int i = 0; i < 8; ++i) {                                               \
        int e = flat + i * 512;                                                 \
        f32x4 v = {0.f, 0.f, 0.f, 0.f};                                         \
        if (e < NF4) {                                                          \
            int col = e >> 4, tq = e & 15;                                      \
            int c = c0 - RT + col;                                              \
            if (c >= 0 && c < C_)                                               \
                v = *(const f32x4*)(xb + (size_t)c * T_ + (T0_) + tq * 4);      \
        }                                                                       \
        stg[i] = v;                                                             \
    }

#define STAGE_WRITE()                                                           \
    _Pragma("unroll")                                                           \
    for (int i = 0; i < 8; ++i) {                                               \
        int e = flat + i * 512;                                                 \
        if (e < NF4) {                                                          \
            int col = e >> 4, tq = e & 15;                                      \
            f32x2 lo = stg[i].xy;   /* t = 4tq,   4tq+1 -> rowpair 2tq   */     \
            f32x2 hi = stg[i].zw;   /* t = 4tq+2, 4tq+3 -> rowpair 2tq+1 */     \
            *(f32x2*)(xsT2 + (2 * tq + 0) * XSTR2 + 2 * col) = lo;              \
            *(f32x2*)(xsT2 + (2 * tq + 1) * XSTR2 + 2 * col) = hi;              \
        }                                                                       \
    }

    STAGE_LOAD(0);

    float mem = 0.0f;                  // channel c0+4g+tp (lanes tp<4)
    float rc  = 0.0f;                  // carried reset (= previous spike)
    float* sbase = IsS + g * (KC * ISTR);
    const f32x4* wq4 = (const f32x4*)wtap;
    const f32x4* xr4 = (const f32x4*)(xsT2 + (size_t)tp * XSTR2 + 8 * g);

#pragma unroll 1
    for (int kk = 0; kk < T_ / TT; ++kk) {
        STAGE_WRITE();          // chunk kk -> xsT2 (vmcnt auto)
        __syncthreads();        // staged tile (+ taps on kk==0) visible

        if (kk < T_ / TT - 1) { STAGE_LOAD((kk + 1) * TT); }  // hides under conv

        // ---- conv: 94 b128 x-reads, 752 pk-fma (2 outputs each) ----
        f32x2 acc[KC];
#pragma unroll
        for (int k = 0; k < KC; ++k) acc[k] = (f32x2){0.f, 0.f};

        PASS(0);  PASS(1);  PASS(2);  PASS(3);  PASS(4);
        PASS(5);  PASS(6);  PASS(7);  PASS(8);  PASS(9);
        PASS(10); PASS(11); PASS(12); PASS(13); PASS(14);
        PASSL();                          // ascending j, exact per-output chain

        // I = x - conv (own cols L=92+k); per-component f32 sub
        {
            f32x4 xoA = xr4[46];          // cols L=92,93 (CSEs with PASS(7))
            f32x4 xoB = xr4[47];          // cols L=94,95
            f32x2 I0 = xoA.xy - acc[0];
            f32x2 I1 = xoA.zw - acc[1];
            f32x2 I2 = xoB.xy - acc[2];
            f32x2 I3 = xoB.zw - acc[3];
            *(f32x2*)(sbase + 0 * ISTR + 2 * tp) = I0;
            *(f32x2*)(sbase + 1 * ISTR + 2 * tp) = I1;
            *(f32x2*)(sbase + 2 * ISTR + 2 * tp) = I2;
            *(f32x2*)(sbase + 3 * ISTR + 2 * tp) = I3;
        }

        // ---- wave-local LIF scan (lanes tp<4; channel c0+4g+tp) ----
        // reset = RN(soft + RN(1-soft)) == 1.0f exactly for soft in (0,0.5):
        // the atan surrogate is bit-exactly a compare; reset_{t+1} == spike_t.
        if (tp < KC) {
            float m = mem, r = rc;
            const float* srow = sbase + tp * ISTR;
            float* orow = ob + (size_t)(c0 + 4 * g + tp) * T_ + (size_t)kk * TT;
#pragma unroll 4
            for (int q = 0; q < TT / 4; ++q) {
                f32x2 ia = *(const f32x2*)(srow + 4 * q);
                f32x2 ib = *(const f32x2*)(srow + 4 * q + 2);
                f32x4 s;
#pragma unroll
                for (int qq = 0; qq < 4; ++qq) {
                    float Ivv = (qq == 0) ? ia.x : (qq == 1) ? ia.y
                              : (qq == 2) ? ib.x : ib.y;
                    m = __fsub_rn(__fadd_rn(__fmul_rn(0.95f, m), Ivv), r);
                    float sp = (m > 1.0f) ? 1.0f : 0.0f;
                    r = sp;
                    if (qq == 0) s.x = sp; else if (qq == 1) s.y = sp;
                    else if (qq == 2) s.z = sp; else s.w = sp;
                }
                *(f32x4*)(orow + 4 * q) = s;
            }
            mem = m; rc = r;
        }
        __syncthreads();        // all conv xsT2 reads done before next STAGE_WRITE
    }
#undef STAGE_LOAD
#undef STAGE_WRITE
}

extern "C" void kernel_launch(void* const* d_in, const int* in_sizes, int n_in,
                              void* d_out, int out_size, void* d_ws, size_t ws_size,
                              hipStream_t stream) {
    const float* x     = (const float*)d_in[0];   // [32,1024,1024] f32
    const float* sigma = (const float*)d_in[1];   // [1] f32
    float* out = (float*)d_out;

    dim3 grid(C_ / CT, B_);   // (16, 32) = 512 blocks, 2/CU
    dim3 block(32, NG);       // 512 threads, 8 waves

    snn_v12<<<grid, block, 0, stream>>>(x, sigma, out);
}

// Round 13
// 178.192 us; speedup vs baseline: 1.1197x; 1.1197x over previous
//
#include <hip/hip_runtime.h>
#include <math.h>

// B,C,T = 32,1024,1024; beta=0.95; thr=1.0; sigma=10.5
#define B_     32
#define C_     1024
#define T_     1024
#define RT     92                    // tap radius (|d|>92 cannot flip any f32 spike; r2-r12)
#define CT     64                    // channels per block
#define TT     64                    // time chunk
#define KC     8                     // channels per thread group
#define NTY    8                     // 8 waves, 512 threads
#define WOFF   (RT + KC - 1)         // 99: tap idx = d + 99, idx in [0,198]
#define NWT    200                   // tap floats (50 quads, rows 0..49 pads)
#define NCOLS  (CT + 2*RT)           // 248 staged channel columns
#define XSTR   252                   // xsT row stride (dwords); cols 248..251 = tap pad
#define ISTR   65                    // I-strip row stride (dwords): conflict-free
#define NF4    (NCOLS * (TT/4))      // 3968 staged float4s per chunk

// numpy-faithful f32 tap (identical op sequence; exp via correctly-rounded f64).
__device__ __forceinline__ float tap_value(float s, int d) {
    float u    = __fdiv_rn((float)d, s);
    float t1   = __fmul_rn(-0.5f, u);
    float t2   = __fmul_rn(t1, u);
    float e    = (float)exp((double)t2);
    float den  = __fmul_rn(s, sqrtf(6.2831854820251465f));
    float coef = __fdiv_rn(1.0f, den);
    return __fmul_rn(coef, e);
}

#define EL(v, i) ((i) == 0 ? (v).x : (i) == 1 ? (v).y : (i) == 2 ? (v).z : (v).w)
#define SEL5(il, T0, T1, T2, T3, T4)                                            \
    ((il) < 4 ? EL(T0, (il)) : (il) < 8 ? EL(T1, (il) - 4)                      \
     : (il) < 12 ? EL(T2, (il) - 8) : (il) < 16 ? EL(T3, (il) - 12)             \
     : EL(T4, (il) - 16))

// One source column (pass-relative cc): 8 FMAs, taps compile-time selected.
#define COL(XV, CC, T0, T1, T2, T3, T4)                                         \
    do {                                                                        \
        float x1_ = EL(XV, (CC) & 3);                                           \
        _Pragma("unroll")                                                       \
        for (int k = 0; k < KC; ++k) {                                          \
            const int il_ = (CC) + 7 - k;                                       \
            acc[k] = fmaf(SEL5(il_, T0, T1, T2, T3, T4), x1_, acc[k]);          \
        }                                                                       \
    } while (0)

// Pass over cols QB*4..QB*4+11 (QB=3p): FIRST issue next pass's 3 x-quads and
// 3 tap-quads into rotating names (latency hides under this pass's 96 FMAs),
// THEN the 12 ascending columns with the current names.
#define PASSX(QB, T0, T1, T2, T3, T4, L0, L1, L2, XA, XB, XC, YA, YB, YC, DOLD) \
    do {                                                                        \
        if (DOLD) {                                                             \
            YA = xq[(QB) + 3]; YB = xq[(QB) + 4]; YC = xq[(QB) + 5];            \
            L0 = TAPQ((QB) + 5); L1 = TAPQ((QB) + 6); L2 = TAPQ((QB) + 7);      \
        }                                                                       \
        COL(XA, 0, T0, T1, T2, T3, T4);  COL(XA, 1, T0, T1, T2, T3, T4);        \
        COL(XA, 2, T0, T1, T2, T3, T4);  COL(XA, 3, T0, T1, T2, T3, T4);        \
        COL(XB, 4, T0, T1, T2, T3, T4);  COL(XB, 5, T0, T1, T2, T3, T4);        \
        COL(XB, 6, T0, T1, T2, T3, T4);  COL(XB, 7, T0, T1, T2, T3, T4);        \
        COL(XC, 8, T0, T1, T2, T3, T4);  COL(XC, 9, T0, T1, T2, T3, T4);        \
        COL(XC, 10, T0, T1, T2, T3, T4); COL(XC, 11, T0, T1, T2, T3, T4);       \
    } while (0)

__global__ __launch_bounds__(512, 4) void snn_v13(
    const float* __restrict__ x, const float* __restrict__ sigma,
    float* __restrict__ out)
{
    __shared__ __align__(16) float xsT[TT * XSTR];       // 64512 B (incl. tap pads)
    __shared__ __align__(16) float IsS[NTY * KC * ISTR]; // 16640 B (total 81152)

    const int tx   = threadIdx.x;      // t lane 0..63
    const int ty   = threadIdx.y;      // wave 0..7
    const int flat = ty * 64 + tx;
    const int b    = blockIdx.y;
    const int c0   = blockIdx.x * CT;
    const int rb   = ty * KC;

    const float* xb = x   + (size_t)b * ((size_t)C_ * T_);
    float*       ob = out + (size_t)b * ((size_t)C_ * T_);

    // ---- taps into xsT row pads (rows 0..49, cols 248..251) ----
    if (flat < NWT) {
        int d = flat - WOFF;
        xsT[(flat >> 2) * XSTR + 248 + (flat & 3)] =
            (d >= -RT && d <= RT) ? tap_value(sigma[0], d) : 0.0f;
    }

    // ---- register staging (proven path): (r = chan col, c4 = t-quad) ----
    float4 stg[2][4];                  // statically indexed only (rule #20)
    const int rB  = (flat >> 2);       // 0..127
    const int c4B = (flat & 3);        // 0..3

#define STAGE_LOAD(T0)                                                          \
    _Pragma("unroll")                                                           \
    for (int i1 = 0; i1 < 2; ++i1) {                                            \
        _Pragma("unroll")                                                       \
        for (int i2 = 0; i2 < 4; ++i2) {                                        \
            int r  = rB + 128 * i1;                                             \
            int c4 = c4B + 4 * i2;                                              \
            int c  = c0 - RT + r;                                               \
            float4 v = make_float4(0.f, 0.f, 0.f, 0.f);                         \
            if (r < NCOLS && c >= 0 && c < C_)                                  \
                v = *(const float4*)(xb + (size_t)c * T_ + (T0) + c4 * 4);      \
            stg[i1][i2] = v;                                                    \
        }                                                                       \
    }

#define STAGE_WRITE()                                                           \
    _Pragma("unroll")                                                           \
    for (int i1 = 0; i1 < 2; ++i1) {                                            \
        _Pragma("unroll")                                                       \
        for (int i2 = 0; i2 < 4; ++i2) {                                        \
            int r  = rB + 128 * i1;                                             \
            int c4 = c4B + 4 * i2;                                              \
            if (r < NCOLS) {                                                    \
                xsT[(4 * c4 + 0) * XSTR + r] = stg[i1][i2].x;                   \
                xsT[(4 * c4 + 1) * XSTR + r] = stg[i1][i2].y;                   \
                xsT[(4 * c4 + 2) * XSTR + r] = stg[i1][i2].z;                   \
                xsT[(4 * c4 + 3) * XSTR + r] = stg[i1][i2].w;                   \
            }                                                                   \
        }                                                                       \
    }

#define TAPQ(Q) (*(const float4*)(xsT + (Q) * XSTR + 248))

    STAGE_LOAD(0);

    float mem = 0.0f;                  // channel c0+rb+tx (lanes tx<8)
    float rc  = 0.0f;                  // carried reset (= previous spike)
    float* strip = IsS + ty * (KC * ISTR);
    const float4* xq = (const float4*)(xsT + tx * XSTR + rb);

#pragma unroll 1
    for (int kk = 0; kk < T_ / TT; ++kk) {
        STAGE_WRITE();          // chunk kk -> xsT (waits its own vmcnt)
        __syncthreads();        // xsT + taps ready for all waves

        if (kk < T_ / TT - 1) { STAGE_LOAD((kk + 1) * TT); }  // lands by next write

        float acc[KC];
#pragma unroll
        for (int k = 0; k < KC; ++k) acc[k] = 0.0f;

        // ---- prologue: pass-0 operands ----
        float4 n0 = TAPQ(0), n1 = TAPQ(1), n2 = TAPQ(2), n3 = TAPQ(3), n4 = TAPQ(4);
        float4 x0 = xq[0], x1 = xq[1], x2 = xq[2];
        float4 n5, n6, n7, x3, x4, x5;

        // ---- 16 software-pipelined passes (rotating names; ascending j) ----
        PASSX(0,  n0,n1,n2,n3,n4, n5,n6,n7, x0,x1,x2, x3,x4,x5, 1);
        PASSX(3,  n3,n4,n5,n6,n7, n0,n1,n2, x3,x4,x5, x0,x1,x2, 1);
        PASSX(6,  n6,n7,n0,n1,n2, n3,n4,n5, x0,x1,x2, x3,x4,x5, 1);
        PASSX(9,  n1,n2,n3,n4,n5, n6,n7,n0, x3,x4,x5, x0,x1,x2, 1);
        PASSX(12, n4,n5,n6,n7,n0, n1,n2,n3, x0,x1,x2, x3,x4,x5, 1);
        PASSX(15, n7,n0,n1,n2,n3, n4,n5,n6, x3,x4,x5, x0,x1,x2, 1);
        PASSX(18, n2,n3,n4,n5,n6, n7,n0,n1, x0,x1,x2, x3,x4,x5, 1);
        PASSX(21, n5,n6,n7,n0,n1, n2,n3,n4, x3,x4,x5, x0,x1,x2, 1);
        PASSX(24, n0,n1,n2,n3,n4, n5,n6,n7, x0,x1,x2, x3,x4,x5, 1);
        PASSX(27, n3,n4,n5,n6,n7, n0,n1,n2, x3,x4,x5, x0,x1,x2, 1);
        PASSX(30, n6,n7,n0,n1,n2, n3,n4,n5, x0,x1,x2, x3,x4,x5, 1);
        PASSX(33, n1,n2,n3,n4,n5, n6,n7,n0, x3,x4,x5, x0,x1,x2, 1);
        PASSX(36, n4,n5,n6,n7,n0, n1,n2,n3, x0,x1,x2, x3,x4,x5, 1);
        PASSX(39, n7,n0,n1,n2,n3, n4,n5,n6, x3,x4,x5, x0,x1,x2, 1);
        PASSX(42, n2,n3,n4,n5,n6, n7,n0,n1, x0,x1,x2, x3,x4,x5, 1);
        PASSX(45, n5,n6,n7,n0,n1, n2,n3,n4, x3,x4,x5, x0,x1,x2, 0);

        // I = x - conv -> wave-local strip (no cross-wave hazard)
        {
            float4 xo0 = xq[RT / 4];        // own x, cols rb+92..95
            float4 xo1 = xq[RT / 4 + 1];    // cols rb+96..99
            strip[0 * ISTR + tx] = __fsub_rn(xo0.x, acc[0]);
            strip[1 * ISTR + tx] = __fsub_rn(xo0.y, acc[1]);
            strip[2 * ISTR + tx] = __fsub_rn(xo0.z, acc[2]);
            strip[3 * ISTR + tx] = __fsub_rn(xo0.w, acc[3]);
            strip[4 * ISTR + tx] = __fsub_rn(xo1.x, acc[4]);
            strip[5 * ISTR + tx] = __fsub_rn(xo1.y, acc[5]);
            strip[6 * ISTR + tx] = __fsub_rn(xo1.z, acc[6]);
            strip[7 * ISTR + tx] = __fsub_rn(xo1.w, acc[7]);
        }

        // ---- wave-local LIF scan (lanes tx<8; channel c0+rb+tx) ----
        // strip is SAME-WAVE data: in-order DS + compiler lgkmcnt suffice, no
        // barrier. reset = RN(soft + RN(1-soft)) == 1.0f exactly for soft in
        // (0,0.5): atan surrogate == compare; reset_{t+1} == spike_t.
        if (tx < KC) {
            float m = mem, r = rc;
            const float* srow = strip + tx * ISTR;
            float* orow = ob + (size_t)(c0 + rb + tx) * T_ + (size_t)kk * TT;
#pragma unroll 4
            for (int q = 0; q < TT / 4; ++q) {
                float4 s;
#pragma unroll
                for (int qq = 0; qq < 4; ++qq) {
                    float Ivv = srow[4 * q + qq];
                    m = __fsub_rn(__fadd_rn(__fmul_rn(0.95f, m), Ivv), r);
                    float sp = (m > 1.0f) ? 1.0f : 0.0f;
                    r = sp;
                    if (qq == 0) s.x = sp; else if (qq == 1) s.y = sp;
                    else if (qq == 2) s.z = sp; else s.w = sp;
                }
                *(float4*)(orow + 4 * q) = s;
            }
            mem = m; rc = r;
        }
        __syncthreads();        // xsT WAR: all waves' reads done before next write
    }
#undef STAGE_LOAD
#undef STAGE_WRITE
#undef TAPQ
}

extern "C" void kernel_launch(void* const* d_in, const int* in_sizes, int n_in,
                              void* d_out, int out_size, void* d_ws, size_t ws_size,
                              hipStream_t stream) {
    const float* x     = (const float*)d_in[0];   // [32,1024,1024] f32
    const float* sigma = (const float*)d_in[1];   // [1] f32
    float* out = (float*)d_out;

    dim3 grid(C_ / CT, B_);   // (16, 32) = 512 blocks, 2/CU
    dim3 block(64, NTY);      // 512 threads, 8 waves

    snn_v13<<<grid, block, 0, stream>>>(x, sigma, out);
}